// Round 3
// baseline (440.090 us; speedup 1.0000x reference)
//
#include <hip/hip_runtime.h>

typedef __bf16 bf16x8 __attribute__((ext_vector_type(8)));
typedef __bf16 bf16x4 __attribute__((ext_vector_type(4)));
typedef float f32x4 __attribute__((ext_vector_type(4)));
typedef short s16x4 __attribute__((ext_vector_type(4)));

union BF4 { bf16x4 b; s16x4 s; };   // bf16 quad <-> v4i16 for mfma_*_1k

// Convert the four 128x128 fp32 weight matrices to bf16 in workspace.
// Wk is PRE-SCALED by (1/sqrt(32))*log2(e): softmax is shift/scale-invariant
// in the right places, so exp2 args arrive pre-scaled for free.
// Layout: Wq @ 0, Wk @ 16384, Wv @ 32768, Wo @ 49152 (elements).
__global__ __launch_bounds__(256) void wcvt(const float* __restrict__ Wq,
                                            const float* __restrict__ Wk,
                                            const float* __restrict__ Wv,
                                            const float* __restrict__ Wo,
                                            __bf16* __restrict__ dst) {
  const float SC = 0.17677669529663687f * 1.4426950408889634f;
  int i = blockIdx.x * 256 + threadIdx.x;    // 0..16383
  dst[i]          = (__bf16)Wq[i];
  dst[16384 + i]  = (__bf16)(Wk[i] * SC);
  dst[32768 + i]  = (__bf16)Wv[i];
  dst[49152 + i]  = (__bf16)Wo[i];
}

// ---------------------------------------------------------------------------
// Fully fused: one block per node, 256 threads = 4 waves, ONE WAVE PER HEAD.
// Fragment identities keep P and V in registers; Q/K transpose through a
// wave-PRIVATE LDS buffer; out-projection fused via a second barrier with the
// priv buffers as the O exchange. This round: arithmetic strength reduction —
// native (__bf16) casts (v_cvt_pk_bf16_f32, RNE) replace manual bit-twiddled
// f2bf; softmax scale folded into Wk/bk; 1/sum folded into P (pre-conversion,
// per-lane — V never rescales); rcp via __builtin_amdgcn_rcpf.
// Barriers per block: 2. LDS: 96*136*2 + 4*96*36*2 = 53760 B -> 3 blocks/CU.
// ---------------------------------------------------------------------------
__global__ __launch_bounds__(256, 3) void attn_k1(
    const float* __restrict__ x, const float* __restrict__ bk,
    const float* __restrict__ bv, const float* __restrict__ bo,
    const __bf16* __restrict__ Wbf, float* __restrict__ out) {
  __shared__ __bf16 Xs[96 * 136];     // x as bf16, padded stride
  __shared__ __bf16 priv[4][96 * 36]; // per-wave Q->K->O buffer

  const int tid  = threadIdx.x;
  const int wid  = tid >> 6;       // 0..3 == head
  const int lane = tid & 63;
  const int quad = lane >> 4;      // 0..3
  const int l16  = lane & 15;
  const int node = blockIdx.x;
  const int h    = wid;
  const float SC = 0.17677669529663687f * 1.4426950408889634f;

  // ---- stage x (fp32 global) -> bf16 LDS, coalesced float4 ----
  const float4* xb = (const float4*)(x + (size_t)node * (96 * 128));
  #pragma unroll
  for (int it = 0; it < 12; ++it) {
    int i4 = tid + it * 256;                 // 0..3071
    float4 v = xb[i4];
    int f = i4 << 2;
    int row = f >> 7, col = f & 127;
    bf16x4 w;
    w[0] = (__bf16)v.x; w[1] = (__bf16)v.y; w[2] = (__bf16)v.z; w[3] = (__bf16)v.w;
    *(bf16x4*)&Xs[row * 136 + col] = w;
  }
  __syncthreads();                           // barrier #1

  __bf16* Bp = &priv[wid][0];
  const __bf16* WqB = Wbf;
  const __bf16* WkB = Wbf + 16384;
  const __bf16* WvB = Wbf + 32768;

  bf16x8 wfr[2][4];

  // ---- V projection: C-frags ARE the PV B-frags (K=16). Keep in regs. ----
  s16x4 vb[6][2];
  {
    #pragma unroll
    for (int nt = 0; nt < 2; ++nt)
      #pragma unroll
      for (int ks = 0; ks < 4; ++ks)
        wfr[nt][ks] = *(const bf16x8*)(WvB + (size_t)(h * 32 + nt * 16 + l16) * 128 + ks * 32 + quad * 8);
    f32x4 vacc[6][2];
    #pragma unroll
    for (int mt = 0; mt < 6; ++mt) { vacc[mt][0] = (f32x4){0,0,0,0}; vacc[mt][1] = (f32x4){0,0,0,0}; }
    #pragma unroll
    for (int mt = 0; mt < 6; ++mt)
      #pragma unroll
      for (int ks = 0; ks < 4; ++ks) {
        bf16x8 afr = *(const bf16x8*)&Xs[(mt * 16 + l16) * 136 + ks * 32 + quad * 8];
        vacc[mt][0] = __builtin_amdgcn_mfma_f32_16x16x32_bf16(afr, wfr[0][ks], vacc[mt][0], 0, 0, 0);
        vacc[mt][1] = __builtin_amdgcn_mfma_f32_16x16x32_bf16(afr, wfr[1][ks], vacc[mt][1], 0, 0, 0);
      }
    float bv0 = bv[h * 32 + l16], bv1 = bv[h * 32 + 16 + l16];
    #pragma unroll
    for (int kt = 0; kt < 6; ++kt) {
      BF4 v0, v1;
      #pragma unroll
      for (int r = 0; r < 4; ++r) {
        v0.b[r] = (__bf16)(vacc[kt][0][r] + bv0);
        v1.b[r] = (__bf16)(vacc[kt][1][r] + bv1);
      }
      vb[kt][0] = v0.s;
      vb[kt][1] = v1.s;
    }
  }

  // ---- Q projection -> private LDS (transpose) -> B-frags in regs ----
  // bq cancels in softmax-over-q, skip it.
  {
    #pragma unroll
    for (int nt = 0; nt < 2; ++nt)
      #pragma unroll
      for (int ks = 0; ks < 4; ++ks)
        wfr[nt][ks] = *(const bf16x8*)(WqB + (size_t)(h * 32 + nt * 16 + l16) * 128 + ks * 32 + quad * 8);
    #pragma unroll
    for (int mt = 0; mt < 6; ++mt) {
      f32x4 a0 = {0,0,0,0}, a1 = {0,0,0,0};
      #pragma unroll
      for (int ks = 0; ks < 4; ++ks) {
        bf16x8 afr = *(const bf16x8*)&Xs[(mt * 16 + l16) * 136 + ks * 32 + quad * 8];
        a0 = __builtin_amdgcn_mfma_f32_16x16x32_bf16(afr, wfr[0][ks], a0, 0, 0, 0);
        a1 = __builtin_amdgcn_mfma_f32_16x16x32_bf16(afr, wfr[1][ks], a1, 0, 0, 0);
      }
      #pragma unroll
      for (int r = 0; r < 4; ++r) {
        Bp[(mt * 16 + quad * 4 + r) * 36 + l16]      = (__bf16)a0[r];
        Bp[(mt * 16 + quad * 4 + r) * 36 + 16 + l16] = (__bf16)a1[r];
      }
    }
  }
  union U16 { uint2 u[2]; bf16x8 v; };
  bf16x8 qb[6];
  #pragma unroll
  for (int qt = 0; qt < 6; ++qt) {
    // stride 36 shorts = 72 B: rows are 8B-aligned, read as two b64s
    const __bf16* p = &Bp[(qt * 16 + l16) * 36 + quad * 8];
    U16 t; t.u[0] = *(const uint2*)p; t.u[1] = *(const uint2*)(p + 4);
    qb[qt] = t.v;
  }

  // ---- K projection -> SAME private buffer (Q already in regs) ----
  // Wk/bk pre-scaled by SC -> exp2 args need no multiply later.
  {
    #pragma unroll
    for (int nt = 0; nt < 2; ++nt)
      #pragma unroll
      for (int ks = 0; ks < 4; ++ks)
        wfr[nt][ks] = *(const bf16x8*)(WkB + (size_t)(h * 32 + nt * 16 + l16) * 128 + ks * 32 + quad * 8);
    float bk0 = bk[h * 32 + l16] * SC, bk1 = bk[h * 32 + 16 + l16] * SC;
    #pragma unroll
    for (int kt = 0; kt < 6; ++kt) {
      f32x4 a0 = {0,0,0,0}, a1 = {0,0,0,0};
      #pragma unroll
      for (int ks = 0; ks < 4; ++ks) {
        bf16x8 afr = *(const bf16x8*)&Xs[(kt * 16 + l16) * 136 + ks * 32 + quad * 8];
        a0 = __builtin_amdgcn_mfma_f32_16x16x32_bf16(afr, wfr[0][ks], a0, 0, 0, 0);
        a1 = __builtin_amdgcn_mfma_f32_16x16x32_bf16(afr, wfr[1][ks], a1, 0, 0, 0);
      }
      #pragma unroll
      for (int r = 0; r < 4; ++r) {
        Bp[(kt * 16 + quad * 4 + r) * 36 + l16]      = (__bf16)(a0[r] + bk0);
        Bp[(kt * 16 + quad * 4 + r) * 36 + 16 + l16] = (__bf16)(a1[r] + bk1);
      }
    }
  }

  // ---- attention: per 16-row k-band; P and V never touch LDS ----
  // softmax over q, no max-subtraction (|s| small, exp2 safe; exact by
  // shift-invariance). 1/sum folds into P before its one bf16 conversion.
  f32x4 o[6][2];
  #pragma unroll
  for (int qt = 0; qt < 6; ++qt) { o[qt][0] = (f32x4){0,0,0,0}; o[qt][1] = (f32x4){0,0,0,0}; }

  #pragma unroll
  for (int band = 0; band < 6; ++band) {
    const __bf16* kp = &Bp[(band * 16 + l16) * 36 + quad * 8];
    U16 tk; tk.u[0] = *(const uint2*)kp; tk.u[1] = *(const uint2*)(kp + 4);
    bf16x8 ka = tk.v;

    float sum0 = 0.f, sum1 = 0.f, sum2 = 0.f, sum3 = 0.f;
    f32x4 ev[6];
    #pragma unroll
    for (int qt = 0; qt < 6; ++qt) {
      f32x4 z = {0,0,0,0};
      f32x4 s = __builtin_amdgcn_mfma_f32_16x16x32_bf16(ka, qb[qt], z, 0, 0, 0);
      f32x4 e;
      e[0] = exp2f(s[0]); e[1] = exp2f(s[1]);
      e[2] = exp2f(s[2]); e[3] = exp2f(s[3]);
      sum0 += e[0]; sum1 += e[1]; sum2 += e[2]; sum3 += e[3];
      ev[qt] = e;
    }
    #pragma unroll
    for (int d = 1; d < 16; d <<= 1) {
      sum0 += __shfl_xor(sum0, d, 64);
      sum1 += __shfl_xor(sum1, d, 64);
      sum2 += __shfl_xor(sum2, d, 64);
      sum3 += __shfl_xor(sum3, d, 64);
    }
    float r0 = __builtin_amdgcn_rcpf(sum0), r1 = __builtin_amdgcn_rcpf(sum1);
    float r2 = __builtin_amdgcn_rcpf(sum2), r3 = __builtin_amdgcn_rcpf(sum3);
    #pragma unroll
    for (int qt = 0; qt < 6; ++qt) {
      BF4 p;
      p.b[0] = (__bf16)(ev[qt][0] * r0);
      p.b[1] = (__bf16)(ev[qt][1] * r1);
      p.b[2] = (__bf16)(ev[qt][2] * r2);
      p.b[3] = (__bf16)(ev[qt][3] * r3);
      o[qt][0] = __builtin_amdgcn_mfma_f32_16x16x16bf16_1k(p.s, vb[band][0], o[qt][0], 0, 0, 0);
      o[qt][1] = __builtin_amdgcn_mfma_f32_16x16x16bf16_1k(p.s, vb[band][1], o[qt][1], 0, 0, 0);
    }
  }

  // ---- park O (96x32 bf16) in OWN priv buffer (K dead; still wave-private)
  #pragma unroll
  for (int qt = 0; qt < 6; ++qt)
    #pragma unroll
    for (int nt = 0; nt < 2; ++nt)
      #pragma unroll
      for (int r = 0; r < 4; ++r)
        Bp[(qt * 16 + quad * 4 + r) * 36 + nt * 16 + l16] = (__bf16)o[qt][nt][r];
  __syncthreads();                           // barrier #2: O exchange

  // ---- fused out-projection: wave w -> output columns [32w, 32w+32) ----
  // A-frag k-slice ks of the 128-dim inner product == head ks's O block.
  {
    const __bf16* WoB = Wbf + 49152;
    bf16x8 wo[2][4];
    #pragma unroll
    for (int nt = 0; nt < 2; ++nt)
      #pragma unroll
      for (int ks = 0; ks < 4; ++ks)
        wo[nt][ks] = *(const bf16x8*)(WoB + (size_t)(wid * 32 + nt * 16 + l16) * 128 + ks * 32 + quad * 8);
    float bo0 = bo[wid * 32 + l16], bo1 = bo[wid * 32 + 16 + l16];
    float* ob = out + (size_t)node * (96 * 128) + wid * 32;
    #pragma unroll
    for (int mt = 0; mt < 6; ++mt) {
      f32x4 a0 = {0,0,0,0}, a1 = {0,0,0,0};
      #pragma unroll
      for (int ks = 0; ks < 4; ++ks) {
        const __bf16* p = &priv[ks][(mt * 16 + l16) * 36 + quad * 8];
        U16 t; t.u[0] = *(const uint2*)p; t.u[1] = *(const uint2*)(p + 4);
        a0 = __builtin_amdgcn_mfma_f32_16x16x32_bf16(t.v, wo[0][ks], a0, 0, 0, 0);
        a1 = __builtin_amdgcn_mfma_f32_16x16x32_bf16(t.v, wo[1][ks], a1, 0, 0, 0);
      }
      #pragma unroll
      for (int r = 0; r < 4; ++r) {
        int row = mt * 16 + quad * 4 + r;
        ob[row * 128 + l16]      = a0[r] + bo0;
        ob[row * 128 + 16 + l16] = a1[r] + bo1;
      }
    }
  }
}

extern "C" void kernel_launch(void* const* d_in, const int* in_sizes, int n_in,
                              void* d_out, int out_size, void* d_ws, size_t ws_size,
                              hipStream_t stream) {
  const float* x  = (const float*)d_in[0];
  const float* Wq = (const float*)d_in[1];
  // d_in[2] = bq: cancels in softmax over q
  const float* Wk = (const float*)d_in[3];
  const float* bk = (const float*)d_in[4];
  const float* Wv = (const float*)d_in[5];
  const float* bv = (const float*)d_in[6];
  const float* Wo = (const float*)d_in[7];
  const float* bo = (const float*)d_in[8];
  int B_N = in_sizes[0] / (96 * 128);        // 4096

  __bf16* Wbf = (__bf16*)d_ws;               // 4 * 16384 bf16 = 128 KiB
  wcvt<<<64, 256, 0, stream>>>(Wq, Wk, Wv, Wo, Wbf);
  attn_k1<<<B_N, 256, 0, stream>>>(x, bk, bv, bo, Wbf, (float*)d_out);
}